// Round 13
// baseline (564.185 us; speedup 1.0000x reference)
//
#include <hip/hip_runtime.h>
#include <hip/hip_bf16.h>
#include <math.h>

#define TOTAL_Q   2048
#define TOTAL_KV  2048
#define QIN       1024
#define KVIN      1033
#define KVIN_P    1056      // KVIN padded to multiple of 32 (zero-filled)
#define DQK       1024
#define DV        1024
#define KVSTR     2048      // fused [k|v] row stride
#define SCALER    0.125f    // 1/sqrt(64)
#define NB        768       // grid = 3 blocks/CU x 256 CUs (co-resident)

typedef __bf16 bf16x8 __attribute__((ext_vector_type(8)));
typedef float  f32x4  __attribute__((ext_vector_type(4)));

// async global->LDS, 16 B per lane; LDS dest = wave-uniform base + lane*16
__device__ __forceinline__ void glds16(const __hip_bfloat16* g, __bf16* l)
{
    __builtin_amdgcn_global_load_lds(
        (const __attribute__((address_space(1))) void*)g,
        (__attribute__((address_space(3))) void*)l,
        16, 0, 0);
}

// XOR-swizzled LDS tile layout (proven R7): slot = quad ^ ((row>>1)&3)
__device__ __forceinline__ int stage_cc(int lane)
{
    return (((lane & 3) ^ ((lane >> 3) & 3)) * 8);
}
__device__ __forceinline__ int frag_off(int row, int quad)
{
    return row * 32 + ((quad ^ ((row >> 1) & 3)) * 8);
}

// Device-scope grid barrier (XCD-safe: agent-scope atomics + threadfence).
// Each id used once per launch; counters zeroed by captured hipMemsetAsync.
__device__ __forceinline__ void gbar(int* cnt, int id)
{
    __syncthreads();
    if (threadIdx.x == 0) {
        __threadfence();   // release: publish this block's writes device-wide
        __hip_atomic_fetch_add(&cnt[id], 1, __ATOMIC_ACQ_REL, __HIP_MEMORY_SCOPE_AGENT);
        while (__hip_atomic_load(&cnt[id], __ATOMIC_ACQUIRE, __HIP_MEMORY_SCOPE_AGENT) < NB)
            __builtin_amdgcn_s_sleep(2);
        __threadfence();   // acquire: invalidate stale caches before reads
    }
    __syncthreads();
}

struct Params {
    const float *A, *B0;
    const int   *seg_q, *seg_kv;
    const float *Wq, *bq, *Wk, *bk, *Wv, *bv, *Wf, *bf;
    float       *out;
    __hip_bfloat16 *B0bf, *Wqt, *Wkt, *Wft, *Abf, *qb, *kvb;  // Wvt = Wkt + 1024*KVIN_P
    int *bar;
};

// ---------------------------------------------------------------------------
// ONE launch, 4 stages, 3 device barriers. Stage bodies = proven R12 kernels.
//   P: casts + weight transposes           (grid-stride over 8320 v-blocks)
//   G: Q + fused-KV projection, XCD-patched (768 blocks 1:1)
//   A: MFMA flash attention                (blocks 0..511)
//   O: out-projection, plain store + bias  (blocks 0..255, XCD-patched)
// LDS: 27.7 KB union, re-aliased per stage (5 blocks/CU LDS-wise).
// ---------------------------------------------------------------------------
__global__ __launch_bounds__(256, 3)
void mega(Params p)
{
    __shared__ __align__(16) char smem[27712];
    const int bid = blockIdx.x;
    const int tid = threadIdx.x;
    const int wave = tid >> 6, lane = tid & 63;
    const int quad = lane >> 4, l16 = lane & 15;
    const int cr = lane >> 2;
    const int cc = stage_cc(lane);

    __hip_bfloat16* Wvt = p.Wkt + (size_t)1024 * KVIN_P;
    __hip_bfloat16* wvb = p.Abf;   // alias: Abf dead after stage G

    // ================= Stage P: prep =================
    {
        float (*tile)[33] = (float(*)[33])smem;
        for (int vb = bid; vb < 8320; vb += NB) {
            if (vb < 2048) {                       // ---- cast A
                int i = (vb * 256 + tid) * 4;
                float4 f = *(const float4*)(p.A + i);
                __hip_bfloat16 o[4] = { __float2bfloat16(f.x), __float2bfloat16(f.y),
                                        __float2bfloat16(f.z), __float2bfloat16(f.w) };
                *(uint2*)(p.Abf + i) = *(const uint2*)o;
            } else if (vb < 4160) {                // ---- cast+pad B0
                int idx = ((vb - 2048) * 256 + tid) * 4;
                int r = idx / KVIN_P, c = idx - r * KVIN_P;
                __hip_bfloat16 o[4];
                #pragma unroll
                for (int j = 0; j < 4; ++j)
                    o[j] = __float2bfloat16((c + j < KVIN) ? p.B0[(size_t)r * KVIN + c + j] : 0.f);
                *(uint2*)(p.B0bf + idx) = *(const uint2*)o;
            } else {                               // ---- weight transposes
                const float* W; __hip_bfloat16* Wt; int K, Kp, k0, n0;
                if (vb < 6208) {
                    int z = vb - 4160;
                    W  = (z >= 1024) ? p.Wf : p.Wq;
                    Wt = (z >= 1024) ? p.Wft : p.Wqt;
                    K = 1024; Kp = 1024;
                    int rem = z & 1023;
                    k0 = (rem & 31) * 32; n0 = (rem >> 5) * 32;
                } else {
                    int z = vb - 6208;
                    W  = (z >= 1056) ? p.Wv : p.Wk;
                    Wt = (z >= 1056) ? Wvt : p.Wkt;
                    K = KVIN; Kp = KVIN_P;
                    int rem = (z >= 1056) ? z - 1056 : z;
                    k0 = (rem % 33) * 32; n0 = (rem / 33) * 32;
                }
                const int tx = tid & 31, ty = tid >> 5;
                #pragma unroll
                for (int i = 0; i < 4; ++i) {
                    int k = k0 + ty + i * 8;
                    tile[ty + i * 8][tx] = (k < K) ? W[(size_t)k * 1024 + n0 + tx] : 0.f;
                }
                __syncthreads();
                #pragma unroll
                for (int i = 0; i < 4; ++i) {
                    int n = n0 + ty + i * 8;
                    Wt[(size_t)n * Kp + k0 + tx] = __float2bfloat16(tile[tx][ty + i * 8]);
                }
                __syncthreads();   // tile reused next iteration
            }
        }
    }
    gbar(p.bar, 0);

    // ================= Stage G: Q + KV projections (XCD-patched) ============
    {
        __bf16* As = (__bf16*)smem;          // 8 KB
        __bf16* Bs = As + 128 * 32;          // 4 KB

        int b = bid;
        const __hip_bfloat16 *Ag, *Btg; const float *bias0, *bias1;
        __hip_bfloat16* C; int N, K, bx, by;
        if (b < 256) {        // Q: 16c x 16r, XCD patch 4x8
            Ag = p.Abf; Btg = p.Wqt; bias0 = p.bq; bias1 = p.bq; C = p.qb;
            N = 1024; K = 1024;
            int xcd = b & 7, i = b >> 3;
            int px = xcd & 3, py = xcd >> 2;
            bx = px * 4 + (i & 3);
            by = py * 8 + (i >> 2);
        } else {              // KV: 32c x 16r, XCD patch 8x8
            b -= 256;
            Ag = p.B0bf; Btg = p.Wkt; bias0 = p.bk; bias1 = p.bv; C = p.kvb;
            N = 2048; K = KVIN_P;
            int xcd = b & 7, i = b >> 3;
            int px = xcd & 3, py = xcd >> 2;
            bx = px * 8 + (i & 7);
            by = py * 8 + (i >> 3);
        }
        const int row0 = by * 128, col0 = bx * 64;
        const int wm = (wave >> 1) * 64, wn = (wave & 1) * 32;

        const __hip_bfloat16* gsrc[3];
        __bf16* ldst[3];
        #pragma unroll
        for (int i = 0; i < 3; ++i) {
            int c = wave * 3 + i;
            if (c < 8) {
                gsrc[i] = Ag  + (size_t)(row0 + c * 16 + cr) * K + cc;
                ldst[i] = &As[c * 512];
            } else {
                gsrc[i] = Btg + (size_t)(col0 + (c - 8) * 16 + cr) * K + cc;
                ldst[i] = &Bs[(c - 8) * 512];
            }
        }

        f32x4 acc[4][2] = {};

        for (int k0 = 0; k0 < K; k0 += 32) {
            #pragma unroll
            for (int i = 0; i < 3; ++i)
                glds16(gsrc[i] + k0, ldst[i]);
            __syncthreads();

            bf16x8 af[4], bfr[2];
            #pragma unroll
            for (int mi = 0; mi < 4; ++mi)
                af[mi] = *(const bf16x8*)&As[frag_off(wm + mi * 16 + l16, quad)];
            #pragma unroll
            for (int ni = 0; ni < 2; ++ni)
                bfr[ni] = *(const bf16x8*)&Bs[frag_off(wn + ni * 16 + l16, quad)];

            #pragma unroll
            for (int mi = 0; mi < 4; ++mi)
                #pragma unroll
                for (int ni = 0; ni < 2; ++ni)
                    acc[mi][ni] = __builtin_amdgcn_mfma_f32_16x16x32_bf16(
                        af[mi], bfr[ni], acc[mi][ni], 0, 0, 0);
            __syncthreads();
        }

        #pragma unroll
        for (int mi = 0; mi < 4; ++mi) {
            #pragma unroll
            for (int ni = 0; ni < 2; ++ni) {
                const int col = col0 + wn + ni * 16 + l16;
                const float bia = (col < 1024) ? bias0[col] : bias1[col - 1024];
                #pragma unroll
                for (int r = 0; r < 4; ++r) {
                    const int row = row0 + wm + mi * 16 + quad * 4 + r;
                    C[(size_t)row * N + col] = __float2bfloat16(acc[mi][ni][r] + bia);
                }
            }
        }
    }
    gbar(p.bar, 1);

    // ================= Stage A: attention (blocks 0..511) ===================
    if (bid < 512) {
        __bf16 (*Ks)[72]     = (__bf16(*)[72])smem;               // 9216 B
        __bf16 (*Vt)[72]     = (__bf16(*)[72])(smem + 9216);      // 9216 B
        __bf16 (*Ps)[16][72] = (__bf16(*)[16][72])(smem + 18432); // 9216 B
        int* sb = (int*)(smem + 27648);

        const int h = bid & 15;
        const int s = bid >> 4;

        if (tid == 0) {
            int lo, hi;
            lo = 0; hi = TOTAL_Q;
            while (lo < hi) { int m = (lo + hi) >> 1; if (p.seg_q[m] <  s) lo = m + 1; else hi = m; }
            sb[0] = lo;
            hi = TOTAL_Q;
            while (lo < hi) { int m = (lo + hi) >> 1; if (p.seg_q[m] <= s) lo = m + 1; else hi = m; }
            sb[1] = lo;
            lo = 0; hi = TOTAL_KV;
            while (lo < hi) { int m = (lo + hi) >> 1; if (p.seg_kv[m] <  s) lo = m + 1; else hi = m; }
            sb[2] = lo;
            hi = TOTAL_KV;
            while (lo < hi) { int m = (lo + hi) >> 1; if (p.seg_kv[m] <= s) lo = m + 1; else hi = m; }
            sb[3] = lo;
        }
        __syncthreads();
        const int qbeg = sb[0], qend = sb[1], kbeg = sb[2], kend = sb[3];

        const __hip_bfloat16* kg = p.kvb;
        const __hip_bfloat16* vg = p.kvb + 1024;

        for (int qt = qbeg; qt < qend; qt += 64) {
            const int qrow = qt + wave * 16 + l16;
            const int qrc  = min(qrow, qend - 1);
            bf16x8 qf[2];
            qf[0] = *(const bf16x8*)(p.qb + (size_t)qrc * DQK + h * 64 + quad * 8);
            qf[1] = *(const bf16x8*)(p.qb + (size_t)qrc * DQK + h * 64 + 32 + quad * 8);

            float m[4]  = { -1e30f, -1e30f, -1e30f, -1e30f };
            float l[4]  = { 0.f, 0.f, 0.f, 0.f };
            f32x4 acc[4] = {};

            for (int c0 = kbeg; c0 < kend; c0 += 64) {
                const int cl = min(64, kend - c0);
                __syncthreads();

                #pragma unroll
                for (int it = 0; it < 2; ++it) {
                    int e = (it * 256 + tid) * 8;
                    int r = e >> 6, d = e & 63;
                    bf16x8 z = {};
                    if (r < cl)
                        z = *(const bf16x8*)(kg + (size_t)(c0 + r) * KVSTR + h * 64 + d);
                    *(bf16x8*)&Ks[r][d] = z;
                }
                #pragma unroll
                for (int it = 0; it < 4; ++it) {
                    int e = (it * 256 + tid) * 4;
                    int r = e >> 6, d = e & 63;
                    __bf16 t0 = 0, t1 = 0, t2 = 0, t3 = 0;
                    if (r < cl) {
                        bf16x8 vv;
                        uint2 uu = *(const uint2*)(vg + (size_t)(c0 + r) * KVSTR + h * 64 + d);
                        *(uint2*)&vv = uu;
                        t0 = vv[0]; t1 = vv[1]; t2 = vv[2]; t3 = vv[3];
                    }
                    Vt[d + 0][r] = t0; Vt[d + 1][r] = t1;
                    Vt[d + 2][r] = t2; Vt[d + 3][r] = t3;
                }
                __syncthreads();

                f32x4 sc[4];
                #pragma unroll
                for (int t = 0; t < 4; ++t) {
                    bf16x8 b0 = *(const bf16x8*)&Ks[t * 16 + l16][quad * 8];
                    bf16x8 b1 = *(const bf16x8*)&Ks[t * 16 + l16][32 + quad * 8];
                    f32x4 z = {};
                    z = __builtin_amdgcn_mfma_f32_16x16x32_bf16(qf[0], b0, z, 0, 0, 0);
                    z = __builtin_amdgcn_mfma_f32_16x16x32_bf16(qf[1], b1, z, 0, 0, 0);
                    sc[t] = z;
                }

                float sv[4][4];
                #pragma unroll
                for (int t = 0; t < 4; ++t) {
                    const bool ok = (c0 + t * 16 + l16) < kend;
                    #pragma unroll
                    for (int r = 0; r < 4; ++r)
                        sv[t][r] = ok ? sc[t][r] * SCALER : -1e30f;
                }

                #pragma unroll
                for (int r = 0; r < 4; ++r) {
                    float mx = fmaxf(fmaxf(sv[0][r], sv[1][r]), fmaxf(sv[2][r], sv[3][r]));
                    mx = fmaxf(mx, __shfl_xor(mx, 1));
                    mx = fmaxf(mx, __shfl_xor(mx, 2));
                    mx = fmaxf(mx, __shfl_xor(mx, 4));
                    mx = fmaxf(mx, __shfl_xor(mx, 8));
                    const float mn = fmaxf(m[r], mx);
                    const float alpha = __expf(m[r] - mn);
                    m[r] = mn;
                    float rs = 0.f;
                    #pragma unroll
                    for (int t = 0; t < 4; ++t) {
                        const float pw = __expf(sv[t][r] - mn);
                        sv[t][r] = pw;
                        rs += pw;
                    }
                    rs += __shfl_xor(rs, 1);
                    rs += __shfl_xor(rs, 2);
                    rs += __shfl_xor(rs, 4);
                    rs += __shfl_xor(rs, 8);
                    l[r] = l[r] * alpha + rs;
                    #pragma unroll
                    for (int dt = 0; dt < 4; ++dt) acc[dt][r] *= alpha;
                }

                #pragma unroll
                for (int t = 0; t < 4; ++t)
                    #pragma unroll
                    for (int r = 0; r < 4; ++r)
                        Ps[wave][quad * 4 + r][t * 16 + l16] = (__bf16)sv[t][r];
                __syncthreads();

                #pragma unroll
                for (int ks = 0; ks < 2; ++ks) {
                    bf16x8 pa = *(const bf16x8*)&Ps[wave][l16][ks * 32 + quad * 8];
                    #pragma unroll
                    for (int dt = 0; dt < 4; ++dt) {
                        bf16x8 vbf = *(const bf16x8*)&Vt[dt * 16 + l16][ks * 32 + quad * 8];
                        acc[dt] = __builtin_amdgcn_mfma_f32_16x16x32_bf16(pa, vbf, acc[dt], 0, 0, 0);
                    }
                }
            }

            float inv[4];
            #pragma unroll
            for (int r = 0; r < 4; ++r) inv[r] = 1.f / l[r];
            #pragma unroll
            for (int dt = 0; dt < 4; ++dt) {
                #pragma unroll
                for (int r = 0; r < 4; ++r) {
                    const int row = qt + wave * 16 + quad * 4 + r;
                    if (row < qend)
                        wvb[(size_t)row * DV + h * 64 + dt * 16 + l16] =
                            __float2bfloat16(acc[dt][r] * inv[r]);
                }
            }
            __syncthreads();   // LDS reuse in next q-tile
        }
    }
    gbar(p.bar, 2);

    // ================= Stage O: out projection (blocks 0..255) ==============
    if (bid < 256) {
        __bf16* As = (__bf16*)smem;
        __bf16* Bs = As + 128 * 32;

        int b = bid;
        const int xcd = b & 7, i = b >> 3;
        const int px = xcd & 3, py = xcd >> 2;
        const int bx = px * 4 + (i & 3);
        const int by = py * 8 + (i >> 2);

        const int wm = (wave >> 1) * 64, wn = (wave & 1) * 32;
        const int row0 = by * 128, col0 = bx * 64;
        const int K = 1024, N = 1024;

        const __hip_bfloat16* gsrc[3];
        __bf16* ldst[3];
        #pragma unroll
        for (int i2 = 0; i2 < 3; ++i2) {
            int c = wave * 3 + i2;
            if (c < 8) {
                gsrc[i2] = wvb   + (size_t)(row0 + c * 16 + cr) * K + cc;
                ldst[i2] = &As[c * 512];
            } else {
                gsrc[i2] = p.Wft + (size_t)(col0 + (c - 8) * 16 + cr) * K + cc;
                ldst[i2] = &Bs[(c - 8) * 512];
            }
        }

        f32x4 acc[4][2] = {};

        for (int k0 = 0; k0 < K; k0 += 32) {
            #pragma unroll
            for (int i2 = 0; i2 < 3; ++i2)
                glds16(gsrc[i2] + k0, ldst[i2]);
            __syncthreads();

            bf16x8 af[4], bfr[2];
            #pragma unroll
            for (int mi = 0; mi < 4; ++mi)
                af[mi] = *(const bf16x8*)&As[frag_off(wm + mi * 16 + l16, quad)];
            #pragma unroll
            for (int ni = 0; ni < 2; ++ni)
                bfr[ni] = *(const bf16x8*)&Bs[frag_off(wn + ni * 16 + l16, quad)];

            #pragma unroll
            for (int mi = 0; mi < 4; ++mi)
                #pragma unroll
                for (int ni = 0; ni < 2; ++ni)
                    acc[mi][ni] = __builtin_amdgcn_mfma_f32_16x16x32_bf16(
                        af[mi], bfr[ni], acc[mi][ni], 0, 0, 0);
            __syncthreads();
        }

        #pragma unroll
        for (int mi = 0; mi < 4; ++mi) {
            #pragma unroll
            for (int ni = 0; ni < 2; ++ni) {
                const int col = col0 + wn + ni * 16 + l16;
                const float bia = p.bf[col];
                #pragma unroll
                for (int r = 0; r < 4; ++r) {
                    const int row = row0 + wm + mi * 16 + quad * 4 + r;
                    p.out[(size_t)row * N + col] = acc[mi][ni][r] + bia;
                }
            }
        }
    }
}

// ---------------------------------------------------------------------------
extern "C" void kernel_launch(void* const* d_in, const int* in_sizes, int n_in,
                              void* d_out, int out_size, void* d_ws, size_t ws_size,
                              hipStream_t stream)
{
    Params p;
    p.A      = (const float*)d_in[0];
    p.B0     = (const float*)d_in[1];
    p.seg_q  = (const int*)  d_in[2];
    p.seg_kv = (const int*)  d_in[3];
    p.Wq     = (const float*)d_in[4];
    p.bq     = (const float*)d_in[5];
    p.Wk     = (const float*)d_in[6];
    p.bk     = (const float*)d_in[7];
    p.Wv     = (const float*)d_in[8];
    p.bv     = (const float*)d_in[9];
    p.Wf     = (const float*)d_in[10];
    p.bf     = (const float*)d_in[11];
    p.out    = (float*)d_out;

    // Workspace (bf16 elems), ~28.7 MB data; barrier counters at +64 MB
    p.B0bf = (__hip_bfloat16*)d_ws;                        // 2048*1056
    p.Wqt  = p.B0bf + (size_t)TOTAL_KV * KVIN_P;           // 1024*1024
    p.Wkt  = p.Wqt  + (size_t)QIN * DQK;                   // 2x 1024*1056 (Wkt|Wvt)
    p.Wft  = p.Wkt  + (size_t)2 * DQK * KVIN_P;            // 1024*1024
    p.Abf  = p.Wft  + (size_t)DV * QIN;                    // 2048*1024 (aliased as wv after G)
    p.qb   = p.Abf  + (size_t)TOTAL_Q * QIN;               // 2048*1024
    p.kvb  = p.qb   + (size_t)TOTAL_Q * DQK;               // 2048*2048 fused [k|v]
    p.bar  = (int*)((char*)d_ws + ((size_t)64 << 20));

    hipMemsetAsync(p.bar, 0, 16, stream);
    mega<<<dim3(NB), dim3(256), 0, stream>>>(p);
}

// Round 14
// 157.394 us; speedup vs baseline: 3.5845x; 3.5845x over previous
//
#include <hip/hip_runtime.h>
#include <hip/hip_bf16.h>
#include <math.h>

#define TOTAL_Q   2048
#define TOTAL_KV  2048
#define QIN       1024
#define KVIN      1033
#define KVIN_P    1088      // KVIN padded to multiple of 64 (zero-filled)
#define DQK       1024
#define DV        1024
#define KVSTR     2048      // fused [k|v] row stride
#define SCALER    0.125f    // 1/sqrt(64)

typedef __bf16 bf16x8 __attribute__((ext_vector_type(8)));
typedef float  f32x4  __attribute__((ext_vector_type(4)));

// async global->LDS, 16 B per lane; LDS dest = wave-uniform base + lane*16
__device__ __forceinline__ void glds16(const __hip_bfloat16* g, __bf16* l)
{
    __builtin_amdgcn_global_load_lds(
        (const __attribute__((address_space(1))) void*)g,
        (__attribute__((address_space(3))) void*)l,
        16, 0, 0);
}

// XOR-swizzled LDS tile layout (proven R7): slot = quad ^ ((row>>1)&3)
__device__ __forceinline__ int stage_cc(int lane)
{
    return (((lane & 3) ^ ((lane >> 3) & 3)) * 8);
}
__device__ __forceinline__ int frag_off(int row, int quad)
{
    return row * 32 + ((quad ^ ((row >> 1) & 3)) * 8);
}

// ---------------------------------------------------------------------------
// Fused prep: casts + weight transposes. 8448 blocks (KVIN_P=1088 ranges):
//   [0,2048)      : cast A
//   [2048,4224)   : cast+pad B0 -> [2048][1088]
//   [4224,6272)   : transpose Wq|Wf  (Kp=1024)
//   [6272,8448)   : transpose Wk|Wv  (K=1033, Kp=1088; 34 k-tiles x 32 n-tiles)
// ---------------------------------------------------------------------------
__global__ __launch_bounds__(256)
void prep_k(const float* __restrict__ A,  const float* __restrict__ B0,
            const float* __restrict__ Wq, const float* __restrict__ Wk,
            const float* __restrict__ Wv, const float* __restrict__ Wf,
            __hip_bfloat16* __restrict__ Abf, __hip_bfloat16* __restrict__ B0bf,
            __hip_bfloat16* __restrict__ Wqt, __hip_bfloat16* __restrict__ Wkt,
            __hip_bfloat16* __restrict__ Wvt, __hip_bfloat16* __restrict__ Wft)
{
    const int b   = blockIdx.x;
    const int tid = threadIdx.x;

    if (b < 2048) {                       // ---- cast A
        int i = (b * 256 + tid) * 4;
        float4 f = *(const float4*)(A + i);
        __hip_bfloat16 o[4] = { __float2bfloat16(f.x), __float2bfloat16(f.y),
                                __float2bfloat16(f.z), __float2bfloat16(f.w) };
        *(uint2*)(Abf + i) = *(const uint2*)o;
        return;
    }
    if (b < 4224) {                       // ---- cast+pad B0 (1088 % 4 == 0)
        int idx = ((b - 2048) * 256 + tid) * 4;
        int r = idx / KVIN_P, c = idx - r * KVIN_P;
        __hip_bfloat16 o[4];
        #pragma unroll
        for (int j = 0; j < 4; ++j)
            o[j] = __float2bfloat16((c + j < KVIN) ? B0[(size_t)r * KVIN + c + j] : 0.f);
        *(uint2*)(B0bf + idx) = *(const uint2*)o;
        return;
    }

    // ---- transposes: W[K][1024] -> Wt[1024][Kp], zero-fill k >= K
    const float* W; __hip_bfloat16* Wt; int K, Kp, k0, n0;
    if (b < 6272) {
        int z = b - 4224;
        W  = (z >= 1024) ? Wf : Wq;
        Wt = (z >= 1024) ? Wft : Wqt;
        K = 1024; Kp = 1024;
        int rem = z & 1023;
        k0 = (rem & 31) * 32; n0 = (rem >> 5) * 32;
    } else {
        int z = b - 6272;
        W  = (z >= 1088) ? Wv : Wk;
        Wt = (z >= 1088) ? Wvt : Wkt;
        K = KVIN; Kp = KVIN_P;
        int rem = (z >= 1088) ? z - 1088 : z;
        k0 = (rem % 34) * 32; n0 = (rem / 34) * 32;
    }
    const int tx = tid & 31, ty = tid >> 5;   // (32,8)
    __shared__ float tile[32][33];
    #pragma unroll
    for (int i = 0; i < 4; ++i) {
        int k = k0 + ty + i * 8;
        tile[ty + i * 8][tx] = (k < K) ? W[(size_t)k * 1024 + n0 + tx] : 0.f;
    }
    __syncthreads();
    #pragma unroll
    for (int i = 0; i < 4; ++i) {
        int n = n0 + ty + i * 8;
        Wt[(size_t)n * Kp + k0 + tx] = __float2bfloat16(tile[tx][ty + i * 8]);
    }
}

// ---------------------------------------------------------------------------
// Grouped Q + fused-KV projection, BK=64 (two BK=32 sub-tiles per barrier
// pair -> 17 drains instead of 33). XCD-patched, BM=128, BN=64, 768 blocks.
// LDS 24 KB: As[2][128*32] + Bs[2][64*32] (index = k-half, layouts proven).
// ---------------------------------------------------------------------------
__global__ __launch_bounds__(256)
void gemm_qkv(const __hip_bfloat16* __restrict__ Abf,
              const __hip_bfloat16* __restrict__ Wqt,
              const float* __restrict__ bq,
              __hip_bfloat16* __restrict__ qb,
              const __hip_bfloat16* __restrict__ B0bf,
              const __hip_bfloat16* __restrict__ Wkvt,
              const float* __restrict__ bk, const float* __restrict__ bv,
              __hip_bfloat16* __restrict__ kvb)
{
    __shared__ __bf16 As[2][128 * 32];   // 16 KB (two k-halves)
    __shared__ __bf16 Bs[2][64 * 32];    // 8 KB

    int b = blockIdx.x;
    const __hip_bfloat16 *Ag, *Btg; const float *bias0, *bias1;
    __hip_bfloat16* C; int N, K, bx, by;
    if (b < 256) {        // Q: 16c x 16r, XCD patch 4x8
        Ag = Abf; Btg = Wqt; bias0 = bq; bias1 = bq; C = qb;
        N = 1024; K = 1024;
        int xcd = b & 7, i = b >> 3;
        int px = xcd & 3, py = xcd >> 2;
        bx = px * 4 + (i & 3);
        by = py * 8 + (i >> 2);
    } else {              // KV: 32c x 16r, XCD patch 8x8
        b -= 256;
        Ag = B0bf; Btg = Wkvt; bias0 = bk; bias1 = bv; C = kvb;
        N = 2048; K = KVIN_P;
        int xcd = b & 7, i = b >> 3;
        int px = xcd & 3, py = xcd >> 2;
        bx = px * 8 + (i & 7);
        by = py * 8 + (i >> 3);
    }
    const int row0 = by * 128, col0 = bx * 64;

    const int tid  = threadIdx.x;
    const int wave = tid >> 6, lane = tid & 63;
    const int quad = lane >> 4, l16 = lane & 15;
    const int wm = (wave >> 1) * 64, wn = (wave & 1) * 32;

    const int cr = lane >> 2;
    const int cc = stage_cc(lane);

    const __hip_bfloat16* gsrc[3];
    __bf16* ldst0[3];
    __bf16* ldst1[3];
    #pragma unroll
    for (int i = 0; i < 3; ++i) {
        int c = wave * 3 + i;
        if (c < 8) {
            gsrc[i]  = Ag + (size_t)(row0 + c * 16 + cr) * K + cc;
            ldst0[i] = &As[0][c * 512];
            ldst1[i] = &As[1][c * 512];
        } else {
            gsrc[i]  = Btg + (size_t)(col0 + (c - 8) * 16 + cr) * K + cc;
            ldst0[i] = &Bs[0][(c - 8) * 512];
            ldst1[i] = &Bs[1][(c - 8) * 512];
        }
    }

    f32x4 acc[4][2] = {};

    for (int k0 = 0; k0 < K; k0 += 64) {
        #pragma unroll
        for (int i = 0; i < 3; ++i) {
            glds16(gsrc[i] + k0,      ldst0[i]);
            glds16(gsrc[i] + k0 + 32, ldst1[i]);
        }
        __syncthreads();

        #pragma unroll
        for (int h = 0; h < 2; ++h) {
            bf16x8 af[4], bfr[2];
            #pragma unroll
            for (int mi = 0; mi < 4; ++mi)
                af[mi] = *(const bf16x8*)&As[h][frag_off(wm + mi * 16 + l16, quad)];
            #pragma unroll
            for (int ni = 0; ni < 2; ++ni)
                bfr[ni] = *(const bf16x8*)&Bs[h][frag_off(wn + ni * 16 + l16, quad)];

            #pragma unroll
            for (int mi = 0; mi < 4; ++mi)
                #pragma unroll
                for (int ni = 0; ni < 2; ++ni)
                    acc[mi][ni] = __builtin_amdgcn_mfma_f32_16x16x32_bf16(
                        af[mi], bfr[ni], acc[mi][ni], 0, 0, 0);
        }
        __syncthreads();
    }

    #pragma unroll
    for (int mi = 0; mi < 4; ++mi) {
        #pragma unroll
        for (int ni = 0; ni < 2; ++ni) {
            const int col = col0 + wn + ni * 16 + l16;
            const float bia = (col < 1024) ? bias0[col] : bias1[col - 1024];
            #pragma unroll
            for (int r = 0; r < 4; ++r) {
                const int row = row0 + wm + mi * 16 + quad * 4 + r;
                C[(size_t)row * N + col] = __float2bfloat16(acc[mi][ni][r] + bia);
            }
        }
    }
}

// ---------------------------------------------------------------------------
// Output projection: BK=64, plain stores + fused bias, 256 blocks XCD-patched.
// ---------------------------------------------------------------------------
__global__ __launch_bounds__(256)
void gemm_out(const __hip_bfloat16* __restrict__ A,
              const __hip_bfloat16* __restrict__ Bt,
              const float* __restrict__ bias,
              float* __restrict__ C,
              int M, int N, int K)
{
    __shared__ __bf16 As[2][128 * 32];
    __shared__ __bf16 Bs[2][64 * 32];

    int b = blockIdx.x;
    const int xcd = b & 7, i = b >> 3;            // i in [0,32)
    const int px = xcd & 3, py = xcd >> 2;
    const int bx = px * 4 + (i & 3);
    const int by = py * 8 + (i >> 2);

    const int tid  = threadIdx.x;
    const int wave = tid >> 6, lane = tid & 63;
    const int quad = lane >> 4, l16 = lane & 15;
    const int wm = (wave >> 1) * 64;
    const int wn = (wave & 1) * 32;
    const int row0 = by * 128, col0 = bx * 64;

    const int cr = lane >> 2;
    const int cc = stage_cc(lane);

    const __hip_bfloat16* gsrc[3];
    __bf16* ldst0[3];
    __bf16* ldst1[3];
    #pragma unroll
    for (int i2 = 0; i2 < 3; ++i2) {
        int c = wave * 3 + i2;
        if (c < 8) {
            gsrc[i2]  = A + (size_t)(row0 + c * 16 + cr) * K + cc;
            ldst0[i2] = &As[0][c * 512];
            ldst1[i2] = &As[1][c * 512];
        } else {
            gsrc[i2]  = Bt + (size_t)(col0 + (c - 8) * 16 + cr) * K + cc;
            ldst0[i2] = &Bs[0][(c - 8) * 512];
            ldst1[i2] = &Bs[1][(c - 8) * 512];
        }
    }

    f32x4 acc[4][2] = {};

    for (int k0 = 0; k0 < K; k0 += 64) {
        #pragma unroll
        for (int i2 = 0; i2 < 3; ++i2) {
            glds16(gsrc[i2] + k0,      ldst0[i2]);
            glds16(gsrc[i2] + k0 + 32, ldst1[i2]);
        }
        __syncthreads();

        #pragma unroll
        for (int h = 0; h < 2; ++h) {
            bf16x8 af[4], bfr[2];
            #pragma unroll
            for (int mi = 0; mi < 4; ++mi)
                af[mi] = *(const bf16x8*)&As[h][frag_off(wm + mi * 16 + l16, quad)];
            #pragma unroll
            for (int ni = 0; ni < 2; ++ni)
                bfr[ni] = *(const bf16x8*)&Bs[h][frag_off(wn + ni * 16 + l16, quad)];

            #pragma unroll
            for (int mi = 0; mi < 4; ++mi)
                #pragma unroll
                for (int ni = 0; ni < 2; ++ni)
                    acc[mi][ni] = __builtin_amdgcn_mfma_f32_16x16x32_bf16(
                        af[mi], bfr[ni], acc[mi][ni], 0, 0, 0);
        }
        __syncthreads();
    }

    #pragma unroll
    for (int mi = 0; mi < 4; ++mi) {
        #pragma unroll
        for (int ni = 0; ni < 2; ++ni) {
            const int col = col0 + wn + ni * 16 + l16;
            const float bia = bias[col];
            #pragma unroll
            for (int r = 0; r < 4; ++r) {
                const int row = row0 + wm + mi * 16 + quad * 4 + r;
                C[(size_t)row * N + col] = acc[mi][ni][r] + bia;
            }
        }
    }
}

// ---------------------------------------------------------------------------
// MFMA flash attention over ragged segments (unchanged, proven).
// ---------------------------------------------------------------------------
#define CH 64

__global__ __launch_bounds__(256)
void attn_mfma(const __hip_bfloat16* __restrict__ qg,
               const __hip_bfloat16* __restrict__ kg,   // kvb
               const __hip_bfloat16* __restrict__ vg,   // kvb + 1024
               const int* __restrict__ seg_q, const int* __restrict__ seg_kv,
               __hip_bfloat16* __restrict__ wv)
{
    const int h = blockIdx.x & 15;
    const int s = blockIdx.x >> 4;

    __shared__ int sb[4];
    __shared__ __bf16 Ks[CH][72];
    __shared__ __bf16 Vt[64][CH + 8];
    __shared__ __bf16 Ps[4][16][CH + 8];

    if (threadIdx.x == 0) {
        int lo, hi;
        lo = 0; hi = TOTAL_Q;
        while (lo < hi) { int m = (lo + hi) >> 1; if (seg_q[m] <  s) lo = m + 1; else hi = m; }
        sb[0] = lo;
        hi = TOTAL_Q;
        while (lo < hi) { int m = (lo + hi) >> 1; if (seg_q[m] <= s) lo = m + 1; else hi = m; }
        sb[1] = lo;
        lo = 0; hi = TOTAL_KV;
        while (lo < hi) { int m = (lo + hi) >> 1; if (seg_kv[m] <  s) lo = m + 1; else hi = m; }
        sb[2] = lo;
        hi = TOTAL_KV;
        while (lo < hi) { int m = (lo + hi) >> 1; if (seg_kv[m] <= s) lo = m + 1; else hi = m; }
        sb[3] = lo;
    }
    __syncthreads();
    const int qbeg = sb[0], qend = sb[1], kbeg = sb[2], kend = sb[3];

    const int tid  = threadIdx.x;
    const int wave = tid >> 6, lane = tid & 63;
    const int quad = lane >> 4, l16 = lane & 15;

    for (int qt = qbeg; qt < qend; qt += 64) {
        const int qrow = qt + wave * 16 + l16;
        const int qrc  = min(qrow, qend - 1);
        bf16x8 qf[2];
        qf[0] = *(const bf16x8*)(qg + (size_t)qrc * DQK + h * 64 + quad * 8);
        qf[1] = *(const bf16x8*)(qg + (size_t)qrc * DQK + h * 64 + 32 + quad * 8);

        float m[4]  = { -1e30f, -1e30f, -1e30f, -1e30f };
        float l[4]  = { 0.f, 0.f, 0.f, 0.f };
        f32x4 acc[4] = {};

        for (int c0 = kbeg; c0 < kend; c0 += CH) {
            const int cl = min(CH, kend - c0);
            __syncthreads();

            #pragma unroll
            for (int it = 0; it < 2; ++it) {
                int e = (it * 256 + tid) * 8;
                int r = e >> 6, d = e & 63;
                bf16x8 z = {};
                if (r < cl)
                    z = *(const bf16x8*)(kg + (size_t)(c0 + r) * KVSTR + h * 64 + d);
                *(bf16x8*)&Ks[r][d] = z;
            }
            #pragma unroll
            for (int it = 0; it < 4; ++it) {
                int e = (it * 256 + tid) * 4;
                int r = e >> 6, d = e & 63;
                __bf16 t0 = 0, t1 = 0, t2 = 0, t3 = 0;
                if (r < cl) {
                    bf16x8 vv;
                    uint2 uu = *(const uint2*)(vg + (size_t)(c0 + r) * KVSTR + h * 64 + d);
                    *(uint2*)&vv = uu;
                    t0 = vv[0]; t1 = vv[1]; t2 = vv[2]; t3 = vv[3];
                }
                Vt[d + 0][r] = t0; Vt[d + 1][r] = t1;
                Vt[d + 2][r] = t2; Vt[d + 3][r] = t3;
            }
            __syncthreads();

            f32x4 sc[4];
            #pragma unroll
            for (int t = 0; t < 4; ++t) {
                bf16x8 b0 = *(const bf16x8*)&Ks[t * 16 + l16][quad * 8];
                bf16x8 b1 = *(const bf16x8*)&Ks[t * 16 + l16][32 + quad * 8];
                f32x4 z = {};
                z = __builtin_amdgcn_mfma_f32_16x16x32_bf16(qf[0], b0, z, 0, 0, 0);
                z = __builtin_amdgcn_mfma_f32_16x16x32_bf16(qf[1], b1, z, 0, 0, 0);
                sc[t] = z;
            }

            float sv[4][4];
            #pragma unroll
            for (int t = 0; t < 4; ++t) {
                const bool ok = (c0 + t * 16 + l16) < kend;
                #pragma unroll
                for (int r = 0; r < 4; ++r)
                    sv[t][r] = ok ? sc[t][r] * SCALER : -1e30f;
            }

            #pragma unroll
            for (int r = 0; r < 4; ++r) {
                float mx = fmaxf(fmaxf(sv[0][r], sv[1][r]), fmaxf(sv[2][r], sv[3][r]));
                mx = fmaxf(mx, __shfl_xor(mx, 1));
                mx = fmaxf(mx, __shfl_xor(mx, 2));
                mx = fmaxf(mx, __shfl_xor(mx, 4));
                mx = fmaxf(mx, __shfl_xor(mx, 8));
                const float mn = fmaxf(m[r], mx);
                const float alpha = __expf(m[r] - mn);
                m[r] = mn;
                float rs = 0.f;
                #pragma unroll
                for (int t = 0; t < 4; ++t) {
                    const float p = __expf(sv[t][r] - mn);
                    sv[t][r] = p;
                    rs += p;
                }
                rs += __shfl_xor(rs, 1);
                rs += __shfl_xor(rs, 2);
                rs += __shfl_xor(rs, 4);
                rs += __shfl_xor(rs, 8);
                l[r] = l[r] * alpha + rs;
                #pragma unroll
                for (int dt = 0; dt < 4; ++dt) acc[dt][r] *= alpha;
            }

            #pragma unroll
            for (int t = 0; t < 4; ++t)
                #pragma unroll
                for (int r = 0; r < 4; ++r)
                    Ps[wave][quad * 4 + r][t * 16 + l16] = (__bf16)sv[t][r];
            __syncthreads();

            #pragma unroll
            for (int ks = 0; ks < 2; ++ks) {
                bf16x8 pa = *(const bf16x8*)&Ps[wave][l16][ks * 32 + quad * 8];
                #pragma unroll
                for (int dt = 0; dt < 4; ++dt) {
                    bf16x8 vbf = *(const bf16x8*)&Vt[dt * 16 + l16][ks * 32 + quad * 8];
                    acc[dt] = __builtin_amdgcn_mfma_f32_16x16x32_bf16(pa, vbf, acc[dt], 0, 0, 0);
                }
            }
        }

        float inv[4];
        #pragma unroll
        for (int r = 0; r < 4; ++r) inv[r] = 1.f / l[r];
        #pragma unroll
        for (int dt = 0; dt < 4; ++dt) {
            #pragma unroll
            for (int r = 0; r < 4; ++r) {
                const int row = qt + wave * 16 + quad * 4 + r;
                if (row < qend)
                    wv[(size_t)row * DV + h * 64 + dt * 16 + l16] =
                        __float2bfloat16(acc[dt][r] * inv[r]);
            }
        }
    }
}

// ---------------------------------------------------------------------------
extern "C" void kernel_launch(void* const* d_in, const int* in_sizes, int n_in,
                              void* d_out, int out_size, void* d_ws, size_t ws_size,
                              hipStream_t stream)
{
    const float* A     = (const float*)d_in[0];
    const float* B0    = (const float*)d_in[1];
    const int*   seg_q = (const int*)  d_in[2];
    const int*   seg_kv= (const int*)  d_in[3];
    const float* Wq    = (const float*)d_in[4];
    const float* bq    = (const float*)d_in[5];
    const float* Wk    = (const float*)d_in[6];
    const float* bk    = (const float*)d_in[7];
    const float* Wv    = (const float*)d_in[8];
    const float* bv    = (const float*)d_in[9];
    const float* Wf    = (const float*)d_in[10];
    const float* bf    = (const float*)d_in[11];
    float* out = (float*)d_out;

    // Workspace (bf16 elems), ~30 MB; all offsets 16B-aligned
    __hip_bfloat16* B0bf = (__hip_bfloat16*)d_ws;                 // 2048*1088
    __hip_bfloat16* Wqt  = B0bf + (size_t)TOTAL_KV * KVIN_P;      // 1024*1024
    __hip_bfloat16* Wkt  = Wqt  + (size_t)QIN * DQK;              // 1024*1088  \ fused
    __hip_bfloat16* Wvt  = Wkt  + (size_t)DQK * KVIN_P;           // 1024*1088  / [2048][1088]
    __hip_bfloat16* Wft  = Wvt  + (size_t)DV * KVIN_P;            // 1024*1024
    __hip_bfloat16* Abf  = Wft  + (size_t)DV * QIN;               // 2048*1024
    __hip_bfloat16* qb   = Abf  + (size_t)TOTAL_Q * QIN;          // 2048*1024
    __hip_bfloat16* kvb  = qb   + (size_t)TOTAL_Q * DQK;          // 2048*2048 fused [k|v]
    __hip_bfloat16* wvb  = Abf;  // alias: Abf dead after grouped QKV GEMM

    const dim3 b256(256);

    // 1) fused prep: casts + weight transposes
    prep_k<<<dim3(8448), b256, 0, stream>>>(A, B0, Wq, Wk, Wv, Wf,
                                            Abf, B0bf, Wqt, Wkt, Wvt, Wft);

    // 2) grouped Q + KV projections (768 blocks; XCD-patched; BK=64)
    gemm_qkv<<<dim3(768), b256, 0, stream>>>(Abf, Wqt, bq, qb,
                                             B0bf, Wkt, bk, bv, kvb);

    // 3) attention: block per (segment, head)
    attn_mfma<<<dim3(32 * 16), b256, 0, stream>>>(qb, kvb, kvb + 1024, seg_q, seg_kv, wvb);

    // 4) output projection: plain store + fused bias (256 blocks, XCD-patched; BK=64)
    gemm_out<<<dim3(256), b256, 0, stream>>>(wvb, Wft, bf, out, TOTAL_Q, QIN, DV);
}